// Round 7
// baseline (283.323 us; speedup 1.0000x reference)
//
#include <hip/hip_runtime.h>
#include <math.h>

#define SEQ 2048
#define DIM 1024
#define HD  128
#define NB  8
#define M_TOT (NB * SEQ)   // 16384

typedef __attribute__((ext_vector_type(8))) short   short8;   // 8 x bf16 (4 VGPRs)
typedef __attribute__((ext_vector_type(4))) float   floatx4;  // MFMA acc

__device__ __forceinline__ unsigned short f2bf(float f) {
    unsigned u = __builtin_bit_cast(unsigned, f);
    u += 0x7FFFu + ((u >> 16) & 1u);
    return (unsigned short)(u >> 16);
}
__device__ __forceinline__ float bf2f(unsigned short h) {
    unsigned u = ((unsigned)h) << 16;
    return __builtin_bit_cast(float, u);
}
__device__ __forceinline__ void async16(const void* g, void* l) {
    __builtin_amdgcn_global_load_lds(
        (const __attribute__((address_space(1))) unsigned int*)g,
        (__attribute__((address_space(3))) unsigned int*)l, 16, 0, 0);
}

#define MFMA16(a, b, c) __builtin_amdgcn_mfma_f32_16x16x32_bf16((a), (b), (c), 0, 0, 0)

// Partial-drain barrier: wait for all but the newest 6 vmem ops (= the
// prefetch batch issued last iter), then rendezvous.  Every wave issues
// exactly 6 async16 per stage() call, so vmcnt(6) drains the batch about to
// be consumed while the in-flight prefetch crosses the barrier.
#define ASYNC_BARRIER() asm volatile("s_waitcnt vmcnt(6) lgkmcnt(0)\n\ts_barrier" ::: "memory")

// ---------------------------------------------------------------------------
// Kernel 0: W -> Wt (transposed, bf16 hi/lo split).  Wt[mat][n=128][k=1024]
// ---------------------------------------------------------------------------
__global__ __launch_bounds__(256) void wt_prep(
    const float* __restrict__ Wq, const float* __restrict__ Wk, const float* __restrict__ Wv,
    unsigned short* __restrict__ Wth, unsigned short* __restrict__ Wtl)
{
    int idx = blockIdx.x * 256 + threadIdx.x;       // [mat][n][k] flat
    int k   = idx & 1023;
    int n   = (idx >> 10) & 127;
    int mat = idx >> 17;
    const float* W = (mat == 0) ? Wq : (mat == 1) ? Wk : Wv;
    float v = W[k * HD + n];
    unsigned short hi = f2bf(v);
    Wth[idx] = hi;
    Wtl[idx] = f2bf(v - bf2f(hi));
}

// ---------------------------------------------------------------------------
// Kernel 1: QKV projection.  grid = (3 mats, 256 mtiles), 256 thr, 4 waves.
// BM=64, BN=128, BK=32.  TRIPLE-buffered LDS (3 x 24 KB = 72 KB, 2 blk/CU),
// prefetch distance 2, ONE partial-drain barrier per iter (vmcnt(6) keeps the
// newest stage batch in flight across the barrier — AITER-style K-loop).
// x staged as RAW FP32 via async16 (zero staging VALU); hi/lo split at
// consume time.  Q,K: bf16x3; V: hi*hi only.
// Frag ids per buf q (1 KB each): A = q*24 + mf*2+c (fp32); B = q*24+8+nf*2+p.
// ---------------------------------------------------------------------------
__global__ __launch_bounds__(256) void qkv_gemm(
    const float* __restrict__ x,
    const unsigned short* __restrict__ Wth, const unsigned short* __restrict__ Wtl,
    const float* __restrict__ bq, const float* __restrict__ bk, const float* __restrict__ bv,
    unsigned short* __restrict__ Qh, unsigned short* __restrict__ Ql,
    unsigned short* __restrict__ Kh, unsigned short* __restrict__ Kl,
    unsigned short* __restrict__ Vt)
{
    __shared__ short lds[72 * 512];                 // 72 KB

    const int t    = threadIdx.x;
    const int lane = t & 63;
    const int w    = t >> 6;
    const int lrow = lane & 15;
    const int quad = lane >> 4;

    const int mat = blockIdx.x;                     // 0=Q 1=K 2=V
    const int R0  = blockIdx.y * 64;
    const int mh  = w & 1;
    const int nh  = w >> 1;

    floatx4 acc[2][4];
    const floatx4 zf = {0.f, 0.f, 0.f, 0.f};
    #pragma unroll
    for (int i = 0; i < 2; ++i)
        #pragma unroll
        for (int j = 0; j < 4; ++j) acc[i][j] = zf;

    const size_t wmat = (size_t)mat * (HD * DIM);

    // wave w stages frag ids w*6 .. w*6+5 (24 frags per buffer, 6 async16/wave)
    auto stage = [&](int k0, int q) {
        #pragma unroll
        for (int i = 0; i < 6; ++i) {
            int id = w * 6 + i;
            const void* src;
            if (id < 8) {                           // A fp32 sub-frag: mf, c
                int mf = id >> 1, c = id & 1;
                src = x + (size_t)(R0 + mf * 16 + lrow) * DIM + k0 + quad * 8 + c * 4;
            } else {                                // B frag: nf, p
                int bid = id - 8, p = bid & 1, nf = bid >> 1;
                src = (p ? Wtl : Wth) + wmat
                    + (size_t)(nf * 16 + lrow) * DIM + k0 + quad * 8;
            }
            async16(src, &lds[(q * 24 + id) * 512 + lane * 8]);
        }
    };

    stage(0, 0);
    stage(32, 1);
    for (int it = 0; it < 32; ++it) {
        ASYNC_BARRIER();                            // buf[it%3] landed; prefetch in flight
        int kn = (it + 2 < 32) ? (it + 2) * 32 : 31 * 32;   // clamped (uniform batch size)
        stage(kn, (it + 2) % 3);
        const int q = it % 3;

        // consume A: fp32 -> hi/lo split in regs
        short8 ah[2], al[2];
        #pragma unroll
        for (int mi = 0; mi < 2; ++mi) {
            int mf = 2 * mh + mi;
            const float* f0 = (const float*)&lds[(q * 24 + mf * 2 + 0) * 512];
            const float* f1 = (const float*)&lds[(q * 24 + mf * 2 + 1) * 512];
            float4 fa = *(const float4*)&f0[lane * 4];
            float4 fb = *(const float4*)&f1[lane * 4];
            float xv[8] = {fa.x, fa.y, fa.z, fa.w, fb.x, fb.y, fb.z, fb.w};
            #pragma unroll
            for (int i = 0; i < 8; ++i) {
                unsigned short h = f2bf(xv[i]);
                ah[mi][i] = (short)h;
                al[mi][i] = (short)f2bf(xv[i] - bf2f(h));
            }
        }
        #pragma unroll
        for (int ni = 0; ni < 4; ++ni) {
            int nf = nh * 4 + ni;
            short8 bh = *(short8*)&lds[(q * 24 + 8 + nf * 2 + 0) * 512 + lane * 8];
            #pragma unroll
            for (int mi = 0; mi < 2; ++mi)
                acc[mi][ni] = MFMA16(ah[mi], bh, acc[mi][ni]);
            if (mat < 2) {                          // uniform branch
                short8 bl = *(short8*)&lds[(q * 24 + 8 + nf * 2 + 1) * 512 + lane * 8];
                #pragma unroll
                for (int mi = 0; mi < 2; ++mi) {
                    acc[mi][ni] = MFMA16(ah[mi], bl, acc[mi][ni]);
                    acc[mi][ni] = MFMA16(al[mi], bh, acc[mi][ni]);
                }
            }
        }
    }

    // epilogue
    const float* bias = (mat == 0) ? bq : (mat == 1) ? bk : bv;
    #pragma unroll
    for (int ni = 0; ni < 4; ++ni) {
        int col = (nh * 4 + ni) * 16 + lrow;
        float bval = bias[col];
        #pragma unroll
        for (int mi = 0; mi < 2; ++mi) {
            #pragma unroll
            for (int reg = 0; reg < 4; ++reg) {
                int gm = R0 + (2 * mh + mi) * 16 + quad * 4 + reg;
                float v = acc[mi][ni][reg] + bval;
                if (mat == 0) {
                    v *= 32.0f;                     // fold sqrt(D)
                    unsigned short h = f2bf(v);
                    Qh[(size_t)gm * HD + col] = h;
                    Ql[(size_t)gm * HD + col] = f2bf(v - bf2f(h));
                } else if (mat == 1) {
                    unsigned short h = f2bf(v);
                    Kh[(size_t)gm * HD + col] = h;
                    Kl[(size_t)gm * HD + col] = f2bf(v - bf2f(h));
                } else {
                    int b = gm >> 11, s = gm & 2047;
                    Vt[((size_t)b * HD + col) * SEQ + s] = f2bf(v);
                }
            }
        }
    }
}

// ---------------------------------------------------------------------------
// Kernel 2: causal flash attention.  64 Q-rows/block, 32-key tiles, each wave
// owns 16 complete rows.  TRIPLE-buffered K/V staging, prefetch distance 2,
// one partial-drain barrier per tile.  Split-K over the tile range (2 halves).
// grid (split=1) = 512: b=idx&7, h=(idx>>3)&1, s=31-(idx>>4) (heavy first).
// T = 2(s+1) tiles; half h covers [h*(s+1), (h+1)*(s+1)).
// LDS frags (1KB): buf q: K = q*24 + nt*8+kc*2+p (16) | V = q*24+16+df (8);
// P = 72 + w.  Total 76 KB -> 2 blocks/CU.
// ---------------------------------------------------------------------------
__global__ __launch_bounds__(256) void flash_attn(
    const unsigned short* __restrict__ Qh, const unsigned short* __restrict__ Ql,
    const unsigned short* __restrict__ Kh, const unsigned short* __restrict__ Kl,
    const unsigned short* __restrict__ Vt, float* __restrict__ out,
    float* __restrict__ Opart, float* __restrict__ ML, int split)
{
    __shared__ short lds[76 * 512];                 // 76 KB

    const int t    = threadIdx.x;
    const int lane = t & 63;
    const int w    = t >> 6;
    const int lrow = lane & 15;
    const int quad = lane >> 4;

    const int idx = blockIdx.x;
    const int b   = idx & 7;
    const int h   = split ? ((idx >> 3) & 1) : 0;
    const int s   = split ? (31 - (idx >> 4)) : (31 - (idx >> 3));
    const int t0  = split ? (h * (s + 1)) : 0;
    const int t1  = t0 + (split ? (s + 1) : (2 * (s + 1)));

    const int R = s * 64 + w * 16;                  // wave's 16 rows (batch-local)

    const size_t kbase = (size_t)b * SEQ * HD;
    const size_t vbase = (size_t)b * HD * SEQ;

    short8 qf[4][2];
    #pragma unroll
    for (int kc = 0; kc < 4; ++kc) {
        size_t off = kbase + (size_t)(R + lrow) * HD + kc * 32 + quad * 8;
        qf[kc][0] = *(const short8*)(Qh + off);
        qf[kc][1] = *(const short8*)(Ql + off);
    }

    const floatx4 zf = {0.f, 0.f, 0.f, 0.f};
    floatx4 accO[8];
    #pragma unroll
    for (int i = 0; i < 8; ++i) accO[i] = zf;
    float m_[4] = {-1e30f, -1e30f, -1e30f, -1e30f};
    float l_[4] = {0.f, 0.f, 0.f, 0.f};

    // wave w stages frag ids w*6 .. w*6+5 (24 frags per buffer, 6 async16/wave)
    auto stage = [&](int tile, int q) {
        const int j0 = tile * 32;
        #pragma unroll
        for (int i = 0; i < 6; ++i) {
            int id = w * 6 + i;
            const unsigned short* src;
            if (id < 16) {                          // K frag: nt, kc, p
                int nt = id >> 3, kc = (id >> 1) & 3, p = id & 1;
                src = (p ? Kl : Kh) + kbase
                    + (size_t)(j0 + nt * 16 + lrow) * HD + kc * 32 + quad * 8;
            } else {                                // V frag: df
                int df = id - 16;
                src = Vt + vbase + (size_t)(df * 16 + lrow) * SEQ + j0 + quad * 8;
            }
            async16(src, &lds[(q * 24 + id) * 512 + lane * 8]);
        }
    };

    stage(t0, 0);
    stage((t0 + 1 < t1) ? t0 + 1 : t1 - 1, 1);
    for (int it = t0; it < t1; ++it) {
        ASYNC_BARRIER();                            // buf[(it-t0)%3] landed
        int st = (it + 2 < t1) ? it + 2 : t1 - 1;   // clamped (uniform batch size)
        stage(st, (it + 2 - t0) % 3);
        const int q  = (it - t0) % 3;
        const int j0 = it * 32;

        if (j0 <= R + 15) {                         // tile not entirely above my rows
            // QK^T (bf16x3) over 32 keys
            floatx4 S[2] = {zf, zf};
            #pragma unroll
            for (int nt = 0; nt < 2; ++nt) {
                #pragma unroll
                for (int kc = 0; kc < 4; ++kc) {
                    short8 khf = *(short8*)&lds[(q * 24 + nt * 8 + kc * 2 + 0) * 512 + lane * 8];
                    short8 klf = *(short8*)&lds[(q * 24 + nt * 8 + kc * 2 + 1) * 512 + lane * 8];
                    S[nt] = MFMA16(qf[kc][0], khf, S[nt]);
                    S[nt] = MFMA16(qf[kc][0], klf, S[nt]);
                    S[nt] = MFMA16(qf[kc][1], khf, S[nt]);
                }
            }
            // causal mask (diagonal tiles only)
            if (j0 + 31 > R) {
                #pragma unroll
                for (int nt = 0; nt < 2; ++nt) {
                    int key = j0 + nt * 16 + lrow;
                    #pragma unroll
                    for (int reg = 0; reg < 4; ++reg) {
                        if (key > R + quad * 4 + reg) S[nt][reg] = -INFINITY;
                    }
                }
            }
            // online softmax (rows fully owned by this wave)
            float alpha[4];
            #pragma unroll
            for (int reg = 0; reg < 4; ++reg) {
                float mx = fmaxf(S[0][reg], S[1][reg]);
                #pragma unroll
                for (int hh = 1; hh < 16; hh <<= 1) mx = fmaxf(mx, __shfl_xor(mx, hh));
                float mnew = fmaxf(fmaxf(m_[reg], mx), -1e30f);
                alpha[reg] = __expf(m_[reg] - mnew);
                m_[reg] = mnew;
                float p0 = __expf(S[0][reg] - mnew);
                float p1 = __expf(S[1][reg] - mnew);
                S[0][reg] = p0; S[1][reg] = p1;
                float ls = p0 + p1;
                #pragma unroll
                for (int hh = 1; hh < 16; hh <<= 1) ls += __shfl_xor(ls, hh);
                l_[reg] = l_[reg] * alpha[reg] + ls;
            }
            #pragma unroll
            for (int i = 0; i < 8; ++i)
                #pragma unroll
                for (int reg = 0; reg < 4; ++reg) accO[i][reg] *= alpha[reg];

            // P: C-layout regs -> A-layout LDS (same-wave round trip)
            #pragma unroll
            for (int nt = 0; nt < 2; ++nt) {
                #pragma unroll
                for (int reg = 0; reg < 4; ++reg) {
                    int kloc = nt * 16 + lrow;       // 0..31
                    int jj = kloc & 7, q2 = (kloc >> 3) & 3;
                    int lane2 = (quad * 4 + reg) + (q2 << 4);
                    lds[(72 + w) * 512 + lane2 * 8 + jj] = (short)f2bf(S[nt][reg]);
                }
            }
            short8 pf = *(short8*)&lds[(72 + w) * 512 + lane * 8];
            #pragma unroll
            for (int df = 0; df < 8; ++df) {
                short8 vf = *(short8*)&lds[(q * 24 + 16 + df) * 512 + lane * 8];
                accO[df] = MFMA16(pf, vf, accO[df]);
            }
        }
    }

    // epilogue (wave owns rows completely)
    if (split) {
        float* op = Opart + (size_t)idx * (64 * 128);
        #pragma unroll
        for (int df = 0; df < 8; ++df) {
            #pragma unroll
            for (int reg = 0; reg < 4; ++reg) {
                int rl = w * 16 + quad * 4 + reg;
                op[rl * 128 + df * 16 + lrow] = accO[df][reg];
            }
        }
        if (lrow == 0) {
            #pragma unroll
            for (int reg = 0; reg < 4; ++reg) {
                int rl = w * 16 + quad * 4 + reg;
                ML[(idx * 64 + rl) * 2 + 0] = m_[reg];
                ML[(idx * 64 + rl) * 2 + 1] = l_[reg];
            }
        }
    } else {
        float inv[4];
        #pragma unroll
        for (int reg = 0; reg < 4; ++reg) inv[reg] = 1.0f / l_[reg];
        #pragma unroll
        for (int df = 0; df < 8; ++df) {
            #pragma unroll
            for (int reg = 0; reg < 4; ++reg) {
                size_t o = ((size_t)(b * SEQ + R + quad * 4 + reg)) * HD + df * 16 + lrow;
                out[o] = accO[df][reg] * inv[reg];
            }
        }
    }
}

// ---------------------------------------------------------------------------
// Kernel 3: split-K merge.  One float4 per thread; 524288 threads.
// ---------------------------------------------------------------------------
__global__ __launch_bounds__(256) void splitk_merge(
    const float* __restrict__ Opart, const float* __restrict__ ML,
    float* __restrict__ out)
{
    int tid = blockIdx.x * 256 + threadIdx.x;
    int row = tid >> 5, c4 = tid & 31;
    int b = row >> 11, r = row & 2047, s = r >> 6, rl = r & 63;
    int i0 = ((31 - s) << 4) + b;                   // h=0 block
    int i1 = i0 + 8;                                // h=1 block
    float m0 = ML[(i0 * 64 + rl) * 2], l0 = ML[(i0 * 64 + rl) * 2 + 1];
    float m1 = ML[(i1 * 64 + rl) * 2], l1 = ML[(i1 * 64 + rl) * 2 + 1];
    float M  = fmaxf(m0, m1);
    float w0 = __expf(m0 - M), w1 = __expf(m1 - M);
    float inv = 1.0f / (w0 * l0 + w1 * l1);
    float4 a  = *(const float4*)&Opart[((size_t)i0 * 64 + rl) * 128 + c4 * 4];
    float4 bb = *(const float4*)&Opart[((size_t)i1 * 64 + rl) * 128 + c4 * 4];
    float4 o;
    o.x = (w0 * a.x + w1 * bb.x) * inv;
    o.y = (w0 * a.y + w1 * bb.y) * inv;
    o.z = (w0 * a.z + w1 * bb.z) * inv;
    o.w = (w0 * a.w + w1 * bb.w) * inv;
    *(float4*)&out[(size_t)row * 128 + c4 * 4] = o;
}

// ---------------------------------------------------------------------------
extern "C" void kernel_launch(void* const* d_in, const int* in_sizes, int n_in,
                              void* d_out, int out_size, void* d_ws, size_t ws_size,
                              hipStream_t stream) {
    const float* x  = (const float*)d_in[0];
    const float* Wq = (const float*)d_in[1];
    const float* bq = (const float*)d_in[2];
    const float* Wk = (const float*)d_in[3];
    const float* bk = (const float*)d_in[4];
    const float* Wv = (const float*)d_in[5];
    const float* bv = (const float*)d_in[6];
    float* out = (float*)d_out;

    unsigned short* Qh  = (unsigned short*)d_ws;
    unsigned short* Ql  = Qh  + (size_t)M_TOT * HD;
    unsigned short* Kh  = Ql  + (size_t)M_TOT * HD;
    unsigned short* Kl  = Kh  + (size_t)M_TOT * HD;
    unsigned short* Vt  = Kl  + (size_t)M_TOT * HD;
    unsigned short* Wth = Vt  + (size_t)M_TOT * HD;
    unsigned short* Wtl = Wth + (size_t)3 * HD * DIM;
    float* Opart = (float*)(Wtl + (size_t)3 * HD * DIM);   // 512 x 64 x 128 f32
    float* ML    = Opart + (size_t)512 * 64 * 128;         // 512 x 64 x 2 f32

    const size_t need = 22544384ULL + 16777216ULL + 262144ULL;   // 39.6 MB
    const int split = (ws_size >= need) ? 1 : 0;

    wt_prep<<<(3 * HD * DIM) / 256, 256, 0, stream>>>(Wq, Wk, Wv, Wth, Wtl);
    qkv_gemm<<<dim3(3, 256), 256, 0, stream>>>(x, Wth, Wtl, bq, bk, bv, Qh, Ql, Kh, Kl, Vt);
    flash_attn<<<split ? 512 : 256, 256, 0, stream>>>(Qh, Ql, Kh, Kl, Vt, out, Opart, ML, split);
    if (split) splitk_merge<<<2048, 256, 0, stream>>>(Opart, ML, out);
}

// Round 9
// 241.035 us; speedup vs baseline: 1.1754x; 1.1754x over previous
//
#include <hip/hip_runtime.h>
#include <math.h>

#define SEQ 2048
#define DIM 1024
#define HD  128
#define NB  8
#define M_TOT (NB * SEQ)   // 16384

typedef __attribute__((ext_vector_type(8))) short   short8;   // 8 x bf16 (4 VGPRs)
typedef __attribute__((ext_vector_type(4))) float   floatx4;  // MFMA acc

__device__ __forceinline__ unsigned short f2bf(float f) {
    unsigned u = __builtin_bit_cast(unsigned, f);
    u += 0x7FFFu + ((u >> 16) & 1u);
    return (unsigned short)(u >> 16);
}
__device__ __forceinline__ float bf2f(unsigned short h) {
    unsigned u = ((unsigned)h) << 16;
    return __builtin_bit_cast(float, u);
}
__device__ __forceinline__ void async16(const void* g, void* l) {
    __builtin_amdgcn_global_load_lds(
        (const __attribute__((address_space(1))) unsigned int*)g,
        (__attribute__((address_space(3))) unsigned int*)l, 16, 0, 0);
}

#define MFMA16(a, b, c) __builtin_amdgcn_mfma_f32_16x16x32_bf16((a), (b), (c), 0, 0, 0)

// ---------------------------------------------------------------------------
// Kernel 0: W -> Wt (transposed, bf16 hi/lo split).  Wt[mat][n=128][k=1024]
// ---------------------------------------------------------------------------
__global__ __launch_bounds__(256) void wt_prep(
    const float* __restrict__ Wq, const float* __restrict__ Wk, const float* __restrict__ Wv,
    unsigned short* __restrict__ Wth, unsigned short* __restrict__ Wtl)
{
    int idx = blockIdx.x * 256 + threadIdx.x;       // [mat][n][k] flat
    int k   = idx & 1023;
    int n   = (idx >> 10) & 127;
    int mat = idx >> 17;
    const float* W = (mat == 0) ? Wq : (mat == 1) ? Wk : Wv;
    float v = W[k * HD + n];
    unsigned short hi = f2bf(v);
    Wth[idx] = hi;
    Wtl[idx] = f2bf(v - bf2f(hi));
}

// ---------------------------------------------------------------------------
// Kernel 1: QKV projection.  grid = (256 mtiles, 3 mats) — mat-major dispatch
// separates the three 64-MB x sweeps temporally (K/V sweeps hit L3).
// 256 thr, 4 waves.  BM=64, BN=128, BK=32, LDS double-buffered (48 KB,
// 3 blk/CU), plain __syncthreads (full drain — counting-proof).
// x register-pipelined with distance 2: loadX(t+2) issues mid-body, drains at
// the NEXT barrier after ~a full MFMA section of flight; writeA(t+1) consumes
// regs loaded one iteration earlier (no zero-distance HBM use).
// Q,K: bf16x3; V: hi*hi only.
// Frag ids per buf q: A = q*24 + mf*2+p (mf=wave); B = q*24+8 + nf*2+p.
// ---------------------------------------------------------------------------
__global__ __launch_bounds__(256) void qkv_gemm(
    const float* __restrict__ x,
    const unsigned short* __restrict__ Wth, const unsigned short* __restrict__ Wtl,
    const float* __restrict__ bq, const float* __restrict__ bk, const float* __restrict__ bv,
    unsigned short* __restrict__ Qh, unsigned short* __restrict__ Ql,
    unsigned short* __restrict__ Kh, unsigned short* __restrict__ Kl,
    unsigned short* __restrict__ Vt)
{
    __shared__ short lds[48 * 512];                 // 48 KB

    const int t    = threadIdx.x;
    const int lane = t & 63;
    const int w    = t >> 6;
    const int lrow = lane & 15;
    const int quad = lane >> 4;

    const int mat = blockIdx.y;                     // 0=Q 1=K 2=V
    const int R0  = blockIdx.x * 64;
    const int mh  = w & 1;
    const int nh  = w >> 1;

    floatx4 acc[2][4];
    const floatx4 zf = {0.f, 0.f, 0.f, 0.f};
    #pragma unroll
    for (int i = 0; i < 2; ++i)
        #pragma unroll
        for (int j = 0; j < 4; ++j) acc[i][j] = zf;

    const size_t wmat = (size_t)mat * (HD * DIM);
    // wave w owns A frag mf=w (16 rows); its x row pointer:
    const float* xp = x + (size_t)(R0 + w * 16 + lrow) * DIM + quad * 8;

    float4 xa, xb;                                  // pipelined x regs
    auto loadX = [&](int k0) {
        xa = *(const float4*)(xp + k0);
        xb = *(const float4*)(xp + k0 + 4);
    };
    auto writeA = [&](int q) {                      // split regs -> LDS frags
        float xv[8] = {xa.x, xa.y, xa.z, xa.w, xb.x, xb.y, xb.z, xb.w};
        short8 hv, lv;
        #pragma unroll
        for (int i = 0; i < 8; ++i) {
            unsigned short h = f2bf(xv[i]);
            hv[i] = (short)h;
            lv[i] = (short)f2bf(xv[i] - bf2f(h));
        }
        *(short8*)&lds[(q * 24 + w * 2 + 0) * 512 + lane * 8] = hv;
        *(short8*)&lds[(q * 24 + w * 2 + 1) * 512 + lane * 8] = lv;
    };
    auto stageB = [&](int k0, int q) {              // wave stages 4 B frags
        #pragma unroll
        for (int i = 0; i < 4; ++i) {
            int id = w * 4 + i;                     // nf*2+p
            int p = id & 1, nf = id >> 1;
            const unsigned short* src = (p ? Wtl : Wth) + wmat
                + (size_t)(nf * 16 + lrow) * DIM + k0 + quad * 8;
            async16(src, &lds[(q * 24 + 8 + id) * 512 + lane * 8]);
        }
    };

    // prologue: tile0 fully staged; x(tile1) in regs
    loadX(0);
    writeA(0);
    stageB(0, 0);
    loadX(32);

    for (int it = 0; it < 32; ++it) {
        __syncthreads();                            // full drain: buf[it&1] ready
        const int q = it & 1;
        if (it + 1 < 32) {
            writeA(1 - q);                          // consumes regs (tile it+1)
            stageB((it + 1) * 32, 1 - q);           // async16, drains next barrier
            if (it + 2 < 32) loadX((it + 2) * 32);  // in flight across the body
        }

        short8 a[2][2];
        #pragma unroll
        for (int mi = 0; mi < 2; ++mi)
            #pragma unroll
            for (int p = 0; p < 2; ++p)
                a[mi][p] = *(short8*)&lds[(q * 24 + (2 * mh + mi) * 2 + p) * 512 + lane * 8];

        #pragma unroll
        for (int ni = 0; ni < 4; ++ni) {
            int nf = nh * 4 + ni;
            short8 bh = *(short8*)&lds[(q * 24 + 8 + nf * 2 + 0) * 512 + lane * 8];
            #pragma unroll
            for (int mi = 0; mi < 2; ++mi)
                acc[mi][ni] = MFMA16(a[mi][0], bh, acc[mi][ni]);
            if (mat < 2) {                          // uniform branch
                short8 bl = *(short8*)&lds[(q * 24 + 8 + nf * 2 + 1) * 512 + lane * 8];
                #pragma unroll
                for (int mi = 0; mi < 2; ++mi) {
                    acc[mi][ni] = MFMA16(a[mi][0], bl, acc[mi][ni]);
                    acc[mi][ni] = MFMA16(a[mi][1], bh, acc[mi][ni]);
                }
            }
        }
    }

    // epilogue
    const float* bias = (mat == 0) ? bq : (mat == 1) ? bk : bv;
    #pragma unroll
    for (int ni = 0; ni < 4; ++ni) {
        int col = (nh * 4 + ni) * 16 + lrow;
        float bval = bias[col];
        #pragma unroll
        for (int mi = 0; mi < 2; ++mi) {
            #pragma unroll
            for (int reg = 0; reg < 4; ++reg) {
                int gm = R0 + (2 * mh + mi) * 16 + quad * 4 + reg;
                float v = acc[mi][ni][reg] + bval;
                if (mat == 0) {
                    v *= 32.0f;                     // fold sqrt(D)
                    unsigned short h = f2bf(v);
                    Qh[(size_t)gm * HD + col] = h;
                    Ql[(size_t)gm * HD + col] = f2bf(v - bf2f(h));
                } else if (mat == 1) {
                    unsigned short h = f2bf(v);
                    Kh[(size_t)gm * HD + col] = h;
                    Kl[(size_t)gm * HD + col] = f2bf(v - bf2f(h));
                } else {
                    int b = gm >> 11, s = gm & 2047;
                    Vt[((size_t)b * HD + col) * SEQ + s] = f2bf(v);
                }
            }
        }
    }
}

// ---------------------------------------------------------------------------
// Kernel 2: causal flash attention (R6 structure — best measured, passing).
// 64 Q-rows/block, 32-key tiles, double-buffered K/V staging, one barrier per
// tile; each wave owns 16 complete rows.  Split-K over tile range (2 halves).
// grid (split=1) = 512: b=idx&7, h=(idx>>3)&1, s=31-(idx>>4) (heavy first).
// LDS frags (1KB): buf q: K = q*24 + nt*8+kc*2+p (16) | V = q*24+16+df (8);
// P = 48 + w.  Total 52 KB -> 3 blocks/CU.
// ---------------------------------------------------------------------------
__global__ __launch_bounds__(256) void flash_attn(
    const unsigned short* __restrict__ Qh, const unsigned short* __restrict__ Ql,
    const unsigned short* __restrict__ Kh, const unsigned short* __restrict__ Kl,
    const unsigned short* __restrict__ Vt, float* __restrict__ out,
    float* __restrict__ Opart, float* __restrict__ ML, int split)
{
    __shared__ short lds[52 * 512];                 // 52 KB

    const int t    = threadIdx.x;
    const int lane = t & 63;
    const int w    = t >> 6;
    const int lrow = lane & 15;
    const int quad = lane >> 4;

    const int idx = blockIdx.x;
    const int b   = idx & 7;
    const int h   = split ? ((idx >> 3) & 1) : 0;
    const int s   = split ? (31 - (idx >> 4)) : (31 - (idx >> 3));
    const int t0  = split ? (h * (s + 1)) : 0;
    const int t1  = t0 + (split ? (s + 1) : (2 * (s + 1)));

    const int R = s * 64 + w * 16;                  // wave's 16 rows (batch-local)

    const size_t kbase = (size_t)b * SEQ * HD;
    const size_t vbase = (size_t)b * HD * SEQ;

    short8 qf[4][2];
    #pragma unroll
    for (int kc = 0; kc < 4; ++kc) {
        size_t off = kbase + (size_t)(R + lrow) * HD + kc * 32 + quad * 8;
        qf[kc][0] = *(const short8*)(Qh + off);
        qf[kc][1] = *(const short8*)(Ql + off);
    }

    const floatx4 zf = {0.f, 0.f, 0.f, 0.f};
    floatx4 accO[8];
    #pragma unroll
    for (int i = 0; i < 8; ++i) accO[i] = zf;
    float m_[4] = {-1e30f, -1e30f, -1e30f, -1e30f};
    float l_[4] = {0.f, 0.f, 0.f, 0.f};

    // wave w stages frag ids w*6 .. w*6+5 (24 frags per buffer)
    auto stage = [&](int tile, int q) {
        const int j0 = tile * 32;
        #pragma unroll
        for (int i = 0; i < 6; ++i) {
            int id = w * 6 + i;
            const unsigned short* src;
            if (id < 16) {                          // K frag: nt, kc, p
                int nt = id >> 3, kc = (id >> 1) & 3, p = id & 1;
                src = (p ? Kl : Kh) + kbase
                    + (size_t)(j0 + nt * 16 + lrow) * HD + kc * 32 + quad * 8;
            } else {                                // V frag: df
                int df = id - 16;
                src = Vt + vbase + (size_t)(df * 16 + lrow) * SEQ + j0 + quad * 8;
            }
            async16(src, &lds[(q * 24 + id) * 512 + lane * 8]);
        }
    };

    stage(t0, 0);
    for (int it = t0; it < t1; ++it) {
        __syncthreads();                            // drains staging of buf[(it-t0)&1]
        if (it + 1 < t1) stage(it + 1, (it + 1 - t0) & 1);
        const int q  = (it - t0) & 1;
        const int j0 = it * 32;

        if (j0 <= R + 15) {                         // tile not entirely above my rows
            // QK^T (bf16x3) over 32 keys
            floatx4 S[2] = {zf, zf};
            #pragma unroll
            for (int nt = 0; nt < 2; ++nt) {
                #pragma unroll
                for (int kc = 0; kc < 4; ++kc) {
                    short8 khf = *(short8*)&lds[(q * 24 + nt * 8 + kc * 2 + 0) * 512 + lane * 8];
                    short8 klf = *(short8*)&lds[(q * 24 + nt * 8 + kc * 2 + 1) * 512 + lane * 8];
                    S[nt] = MFMA16(qf[kc][0], khf, S[nt]);
                    S[nt] = MFMA16(qf[kc][0], klf, S[nt]);
                    S[nt] = MFMA16(qf[kc][1], khf, S[nt]);
                }
            }
            // causal mask (diagonal tiles only)
            if (j0 + 31 > R) {
                #pragma unroll
                for (int nt = 0; nt < 2; ++nt) {
                    int key = j0 + nt * 16 + lrow;
                    #pragma unroll
                    for (int reg = 0; reg < 4; ++reg) {
                        if (key > R + quad * 4 + reg) S[nt][reg] = -INFINITY;
                    }
                }
            }
            // online softmax (rows fully owned by this wave)
            float alpha[4];
            #pragma unroll
            for (int reg = 0; reg < 4; ++reg) {
                float mx = fmaxf(S[0][reg], S[1][reg]);
                #pragma unroll
                for (int hh = 1; hh < 16; hh <<= 1) mx = fmaxf(mx, __shfl_xor(mx, hh));
                float mnew = fmaxf(fmaxf(m_[reg], mx), -1e30f);
                alpha[reg] = __expf(m_[reg] - mnew);
                m_[reg] = mnew;
                float p0 = __expf(S[0][reg] - mnew);
                float p1 = __expf(S[1][reg] - mnew);
                S[0][reg] = p0; S[1][reg] = p1;
                float ls = p0 + p1;
                #pragma unroll
                for (int hh = 1; hh < 16; hh <<= 1) ls += __shfl_xor(ls, hh);
                l_[reg] = l_[reg] * alpha[reg] + ls;
            }
            #pragma unroll
            for (int i = 0; i < 8; ++i)
                #pragma unroll
                for (int reg = 0; reg < 4; ++reg) accO[i][reg] *= alpha[reg];

            // P: C-layout regs -> A-layout LDS (same-wave round trip)
            #pragma unroll
            for (int nt = 0; nt < 2; ++nt) {
                #pragma unroll
                for (int reg = 0; reg < 4; ++reg) {
                    int kloc = nt * 16 + lrow;       // 0..31
                    int jj = kloc & 7, q2 = (kloc >> 3) & 3;
                    int lane2 = (quad * 4 + reg) + (q2 << 4);
                    lds[(48 + w) * 512 + lane2 * 8 + jj] = (short)f2bf(S[nt][reg]);
                }
            }
            short8 pf = *(short8*)&lds[(48 + w) * 512 + lane * 8];
            #pragma unroll
            for (int df = 0; df < 8; ++df) {
                short8 vf = *(short8*)&lds[(q * 24 + 16 + df) * 512 + lane * 8];
                accO[df] = MFMA16(pf, vf, accO[df]);
            }
        }
    }

    // epilogue (wave owns rows completely)
    if (split) {
        float* op = Opart + (size_t)idx * (64 * 128);
        #pragma unroll
        for (int df = 0; df < 8; ++df) {
            #pragma unroll
            for (int reg = 0; reg < 4; ++reg) {
                int rl = w * 16 + quad * 4 + reg;
                op[rl * 128 + df * 16 + lrow] = accO[df][reg];
            }
        }
        if (lrow == 0) {
            #pragma unroll
            for (int reg = 0; reg < 4; ++reg) {
                int rl = w * 16 + quad * 4 + reg;
                ML[(idx * 64 + rl) * 2 + 0] = m_[reg];
                ML[(idx * 64 + rl) * 2 + 1] = l_[reg];
            }
        }
    } else {
        float inv[4];
        #pragma unroll
        for (int reg = 0; reg < 4; ++reg) inv[reg] = 1.0f / l_[reg];
        #pragma unroll
        for (int df = 0; df < 8; ++df) {
            #pragma unroll
            for (int reg = 0; reg < 4; ++reg) {
                size_t o = ((size_t)(b * SEQ + R + quad * 4 + reg)) * HD + df * 16 + lrow;
                out[o] = accO[df][reg] * inv[reg];
            }
        }
    }
}

// ---------------------------------------------------------------------------
// Kernel 3: split-K merge.  One float4 per thread; 524288 threads.
// ---------------------------------------------------------------------------
__global__ __launch_bounds__(256) void splitk_merge(
    const float* __restrict__ Opart, const float* __restrict__ ML,
    float* __restrict__ out)
{
    int tid = blockIdx.x * 256 + threadIdx.x;
    int row = tid >> 5, c4 = tid & 31;
    int b = row >> 11, r = row & 2047, s = r >> 6, rl = r & 63;
    int i0 = ((31 - s) << 4) + b;                   // h=0 block
    int i1 = i0 + 8;                                // h=1 block
    float m0 = ML[(i0 * 64 + rl) * 2], l0 = ML[(i0 * 64 + rl) * 2 + 1];
    float m1 = ML[(i1 * 64 + rl) * 2], l1 = ML[(i1 * 64 + rl) * 2 + 1];
    float M  = fmaxf(m0, m1);
    float w0 = __expf(m0 - M), w1 = __expf(m1 - M);
    float inv = 1.0f / (w0 * l0 + w1 * l1);
    float4 a  = *(const float4*)&Opart[((size_t)i0 * 64 + rl) * 128 + c4 * 4];
    float4 bb = *(const float4*)&Opart[((size_t)i1 * 64 + rl) * 128 + c4 * 4];
    float4 o;
    o.x = (w0 * a.x + w1 * bb.x) * inv;
    o.y = (w0 * a.y + w1 * bb.y) * inv;
    o.z = (w0 * a.z + w1 * bb.z) * inv;
    o.w = (w0 * a.w + w1 * bb.w) * inv;
    *(float4*)&out[(size_t)row * 128 + c4 * 4] = o;
}

// ---------------------------------------------------------------------------
extern "C" void kernel_launch(void* const* d_in, const int* in_sizes, int n_in,
                              void* d_out, int out_size, void* d_ws, size_t ws_size,
                              hipStream_t stream) {
    const float* x  = (const float*)d_in[0];
    const float* Wq = (const float*)d_in[1];
    const float* bq = (const float*)d_in[2];
    const float* Wk = (const float*)d_in[3];
    const float* bk = (const float*)d_in[4];
    const float* Wv = (const float*)d_in[5];
    const float* bv = (const float*)d_in[6];
    float* out = (float*)d_out;

    unsigned short* Qh  = (unsigned short*)d_ws;
    unsigned short* Ql  = Qh  + (size_t)M_TOT * HD;
    unsigned short* Kh  = Ql  + (size_t)M_TOT * HD;
    unsigned short* Kl  = Kh  + (size_t)M_TOT * HD;
    unsigned short* Vt  = Kl  + (size_t)M_TOT * HD;
    unsigned short* Wth = Vt  + (size_t)M_TOT * HD;
    unsigned short* Wtl = Wth + (size_t)3 * HD * DIM;
    float* Opart = (float*)(Wtl + (size_t)3 * HD * DIM);   // 512 x 64 x 128 f32
    float* ML    = Opart + (size_t)512 * 64 * 128;         // 512 x 64 x 2 f32

    const size_t need = 22544384ULL + 16777216ULL + 262144ULL;   // 39.6 MB
    const int split = (ws_size >= need) ? 1 : 0;

    wt_prep<<<(3 * HD * DIM) / 256, 256, 0, stream>>>(Wq, Wk, Wv, Wth, Wtl);
    qkv_gemm<<<dim3(256, 3), 256, 0, stream>>>(x, Wth, Wtl, bq, bk, bv, Qh, Ql, Kh, Kl, Vt);
    flash_attn<<<split ? 512 : 256, 256, 0, stream>>>(Qh, Ql, Kh, Kl, Vt, out, Opart, ML, split);
    if (split) splitk_merge<<<2048, 256, 0, stream>>>(Opart, ML, out);
}